// Round 12
// baseline (198.975 us; speedup 1.0000x reference)
//
#include <hip/hip_runtime.h>
#include <hip/hip_bf16.h>
#include <stdint.h>

#define L_SEQ   4096
#define D_MODEL 1024
#define N_HEADS 16
#define HEAD_DIM 64

typedef uint16_t u16;
typedef __bf16 bf16x8 __attribute__((ext_vector_type(8)));
typedef uint32_t u32x4 __attribute__((ext_vector_type(4)));
typedef float floatx4 __attribute__((ext_vector_type(4)));

__device__ __forceinline__ floatx4 mfma32(bf16x8 a, bf16x8 b, floatx4 c) {
  return __builtin_amdgcn_mfma_f32_16x16x32_bf16(a, b, c, 0, 0, 0);
}

__device__ __forceinline__ float hw_exp2(float x) {
  return __builtin_amdgcn_exp2f(x);
}

__device__ __forceinline__ uint32_t fbits(float f) {
  union { float f; uint32_t u; } x; x.f = f; return x.u;
}

// pack two f32 -> two truncated bf16 in one v_perm_b32
__device__ __forceinline__ uint32_t pack_bf16_trunc(float f1, float f0) {
  return __builtin_amdgcn_perm(fbits(f1), fbits(f0), 0x07060302u);
}

// async global->LDS 16B per lane; LDS dest = wave-uniform base + lane*16
__device__ __forceinline__ void load16_lds(const u16* g, u16* l) {
  __builtin_amdgcn_global_load_lds(
      (const __attribute__((address_space(1))) void*)g,
      (__attribute__((address_space(3))) void*)l, 16, 0, 0);
}

// round-to-nearest-even f32 -> bf16 bits
__device__ __forceinline__ u16 f2bf(float f) {
  uint32_t u = fbits(f);
  uint32_t r = u + 0x7FFFu + ((u >> 16) & 1u);
  return (u16)(r >> 16);
}

// 0.125 * log2(e): folds softmax scale + exp->exp2 conversion into Q.
#define Q_PRESCALE 0.18033688011112042f

// ---------------------------------------------------------------------------
// f32 -> bf16 conversion pre-pass. grid.z selects tensor (0=x, 1..4=W).
// 8 elems/thread (2x float4 read, 2x ushort4 write). (R20-proven)
// ---------------------------------------------------------------------------
__global__ __launch_bounds__(256) void cvt_kernel(
    const float* __restrict__ x,  const float* __restrict__ wq,
    const float* __restrict__ wk, const float* __restrict__ wv,
    const float* __restrict__ wo,
    u16* __restrict__ xb, u16* __restrict__ wqb, u16* __restrict__ wkb,
    u16* __restrict__ wvb, u16* __restrict__ wob) {
  const int z = blockIdx.z;
  const float* s; u16* d; int n;
  if (z == 0)      { s = x;  d = xb;  n = L_SEQ * D_MODEL; }
  else if (z == 1) { s = wq; d = wqb; n = D_MODEL * D_MODEL; }
  else if (z == 2) { s = wk; d = wkb; n = D_MODEL * D_MODEL; }
  else if (z == 3) { s = wv; d = wvb; n = D_MODEL * D_MODEL; }
  else             { s = wo; d = wob; n = D_MODEL * D_MODEL; }
  const int stride = gridDim.x * 256 * 8;
  for (int i = (blockIdx.x * 256 + threadIdx.x) * 8; i < n; i += stride) {
    float4 v0 = *(const float4*)(s + i);
    float4 v1 = *(const float4*)(s + i + 4);
    ushort4 o0, o1;
    o0.x = f2bf(v0.x); o0.y = f2bf(v0.y); o0.z = f2bf(v0.z); o0.w = f2bf(v0.w);
    o1.x = f2bf(v1.x); o1.y = f2bf(v1.y); o1.z = f2bf(v1.z); o1.w = f2bf(v1.w);
    *(ushort4*)(d + i) = o0;
    *(ushort4*)(d + i + 4) = o1;
  }
}

// ---------------------------------------------------------------------------
// Merged Q/K/V^T GEMM. R22 (T4 counted-vmcnt): 3-buffer LDS ring, 2-deep
// prefetch, raw s_barrier + "s_waitcnt vmcnt(2) lgkmcnt(0)". The old
// __syncthreads() forced vmcnt(0) every iter, draining the just-issued
// prefetch (the documented ~20% m97-structure stall). Now only the OLDEST
// stage (the one this iter reads) is retired; the newer stays in flight
// across the barrier. lgkmcnt(0) pre-barrier makes the 3-buffer ring
// race-free: no wave crosses with ds_reads in flight, and the write target
// (kk+2)%3 never equals any buffer still being read. LDS 48 KB -> grid 768
// = 3 blocks/CU all-resident. Compute mapping unchanged (512 thr, 2m x 4n).
// ---------------------------------------------------------------------------
__global__ __launch_bounds__(512) void qkv_gemm_kernel(
    const u16* __restrict__ X,
    const u16* __restrict__ Wq, const u16* __restrict__ Wk, const u16* __restrict__ Wv,
    u16* __restrict__ Qo, u16* __restrict__ Ko, u16* __restrict__ VTo) {
  constexpr int BK = 32, Kdim = D_MODEL, NIT = Kdim / BK;
  __shared__ __align__(16) u16 As[3][128 * BK];
  __shared__ __align__(16) u16 Bs[3][128 * BK];

  const int b = blockIdx.x;
  const int g = b & 7, i2 = b >> 3;
  const int z = i2 % 3, j = i2 / 3;          // z fastest within XCD stream
  const int x = (g & 3) * 8 + (j & 7);       // 32 m-tiles (seq for z<2)
  const int y = (g >> 2) * 4 + (j >> 3);     // 8 n-tiles (dout for z<2)

  const u16* __restrict__ A;
  const u16* __restrict__ B;
  int m0, n0;
  if (z < 2) { A = X; B = z ? Wk : Wq; m0 = x * 128; n0 = y * 128; }
  else       { A = Wv; B = X;          m0 = y * 128; n0 = x * 128; }

  const int tid = threadIdx.x;               // 0..511
  const int wave = tid >> 6, lane = tid & 63;
  const int wm = wave & 1, wn = wave >> 1;   // 2 x 4 wave grid
  const int quad = lane >> 4, l15 = lane & 15;

  floatx4 acc[4][2] = {};

  // staging: thread t covers row t>>2, 8-col chunk (t&3)*8 of the 128x32 tile
  const int r0 = tid >> 2, cc0 = (tid & 3) * 8;

  auto stage = [&](int k0, int sel) {
    load16_lds(&A[(size_t)(m0 + r0) * Kdim + k0 + cc0], &As[sel][wave * 512]);
    load16_lds(&B[(size_t)(n0 + r0) * Kdim + k0 + cc0], &Bs[sel][wave * 512]);
  };

  stage(0, 0);
  stage(BK, 1);
  int cur = 0, nx2 = 2;
  for (int kk = 0; kk < NIT; ++kk) {
    // retire ONLY the oldest stage (2 calls); newer prefetch stays in flight.
    if (kk + 1 < NIT)
      asm volatile("s_waitcnt vmcnt(2) lgkmcnt(0)" ::: "memory");
    else
      asm volatile("s_waitcnt vmcnt(0) lgkmcnt(0)" ::: "memory");
    __builtin_amdgcn_s_barrier();
    if (kk + 2 < NIT) stage((kk + 2) * BK, nx2);

    const u16* Asc = As[cur];
    const u16* Bsc = Bs[cur];

    bf16x8 af[4], wf[2];
#pragma unroll
    for (int i = 0; i < 4; ++i)
      af[i] = *(const bf16x8*)(&Asc[(wm * 64 + i * 16 + l15) * BK + quad * 8]);
#pragma unroll
    for (int jn = 0; jn < 2; ++jn)
      wf[jn] = *(const bf16x8*)(&Bsc[(wn * 32 + jn * 16 + l15) * BK + quad * 8]);
#pragma unroll
    for (int i = 0; i < 4; ++i)
#pragma unroll
      for (int jn = 0; jn < 2; ++jn)
        acc[i][jn] = mfma32(af[i], wf[jn], acc[i][jn]);

    cur = (cur == 2) ? 0 : cur + 1;
    nx2 = (nx2 == 2) ? 0 : nx2 + 1;
  }

  const float scale = (z == 0) ? Q_PRESCALE : 1.0f;
  u16* __restrict__ C = (z == 0) ? Qo : (z == 1) ? Ko : VTo;
#pragma unroll
  for (int i = 0; i < 4; ++i) {
    const int mb = m0 + wm * 64 + i * 16 + quad * 4;
#pragma unroll
    for (int jn = 0; jn < 2; ++jn) {
      const int n = n0 + wn * 32 + jn * 16 + l15;
#pragma unroll
      for (int r = 0; r < 4; ++r) {
        const int m = mb + r;
        if (z < 2) {
          C[(size_t)(n >> 6) * (size_t)L_SEQ * HEAD_DIM + (size_t)m * HEAD_DIM + (n & 63)] =
              f2bf(acc[i][jn][r] * scale);
        } else {
          C[(size_t)(m >> 6) * (size_t)L_SEQ * HEAD_DIM + (size_t)(m & 63) * L_SEQ + n] =
              f2bf(acc[i][jn][r]);
        }
      }
    }
  }
}

// ---------------------------------------------------------------------------
// Output GEMM: out = att @ Wo^T, f32 out. R22: same T4 counted-vmcnt ring as
// qkv. Per-wave load counts differ (waves 0-3: A+B = 2 calls/stage; waves
// 4-7: A only = 1), so the counted wait is wave-uniform-branched: vmcnt(2)
// vs vmcnt(1). XCD-rectangle swizzle (R21) and 512-thread compute (R20) kept.
// ---------------------------------------------------------------------------
__global__ __launch_bounds__(512) void out_gemm_kernel(
    const u16* __restrict__ A, const u16* __restrict__ W, float* __restrict__ C) {
  constexpr int BK = 32, Kdim = D_MODEL, NIT = Kdim / BK;
  __shared__ __align__(16) u16 As[3][128 * BK];
  __shared__ __align__(16) u16 Bs[3][64 * BK];

  const int b = blockIdx.x;
  const int g = b & 7, j = b >> 3;           // XCD, 64 blocks per XCD
  const int m0 = (g * 4 + (j & 3)) * 128;    // 4 m-panels per XCD (1 MB in L2)
  const int n0 = (j >> 2) * 64;              // 16 n-tiles

  const int tid = threadIdx.x;               // 0..511
  const int wave = tid >> 6, lane = tid & 63;
  const int wm = wave & 1, wn = wave >> 1;   // 2m x 4n wave grid
  const int quad = lane >> 4, l15 = lane & 15;

  floatx4 acc[4] = {};

  // staging: thread t covers row t>>2, 8-col chunk (t&3)*8
  const int r0 = tid >> 2, cc0 = (tid & 3) * 8;

  auto stage = [&](int k0, int sel) {
    load16_lds(&A[(size_t)(m0 + r0) * Kdim + k0 + cc0], &As[sel][wave * 512]);
    if (wave < 4)                            // 64-row B tile: waves 0-3
      load16_lds(&W[(size_t)(n0 + r0) * Kdim + k0 + cc0], &Bs[sel][wave * 512]);
  };

  stage(0, 0);
  stage(BK, 1);
  int cur = 0, nx2 = 2;
  for (int kk = 0; kk < NIT; ++kk) {
    if (kk + 1 < NIT) {
      if (wave < 4)
        asm volatile("s_waitcnt vmcnt(2) lgkmcnt(0)" ::: "memory");
      else
        asm volatile("s_waitcnt vmcnt(1) lgkmcnt(0)" ::: "memory");
    } else {
      asm volatile("s_waitcnt vmcnt(0) lgkmcnt(0)" ::: "memory");
    }
    __builtin_amdgcn_s_barrier();
    if (kk + 2 < NIT) stage((kk + 2) * BK, nx2);

    const u16* Asc = As[cur];
    const u16* Bsc = Bs[cur];

    bf16x8 af[4], wf;
#pragma unroll
    for (int i = 0; i < 4; ++i)
      af[i] = *(const bf16x8*)(&Asc[(wm * 64 + i * 16 + l15) * BK + quad * 8]);
    wf = *(const bf16x8*)(&Bsc[(wn * 16 + l15) * BK + quad * 8]);
#pragma unroll
    for (int i = 0; i < 4; ++i)
      acc[i] = mfma32(af[i], wf, acc[i]);

    cur = (cur == 2) ? 0 : cur + 1;
    nx2 = (nx2 == 2) ? 0 : nx2 + 1;
  }

#pragma unroll
  for (int i = 0; i < 4; ++i) {
    const int mb = m0 + wm * 64 + i * 16 + quad * 4;
    const int n = n0 + wn * 16 + l15;
#pragma unroll
    for (int r = 0; r < 4; ++r)
      C[(size_t)(mb + r) * D_MODEL + n] = acc[i][r];
  }
}

// ---------------------------------------------------------------------------
// Causal flash attention (R14 inner loop, single 1024-block dispatch --
// proven 64.5us; all in-structure levers measured null R13-R16). Unchanged.
// ---------------------------------------------------------------------------
#define LDW 136
__global__ __launch_bounds__(256, 2) void attn_kernel(
    const u16* __restrict__ Q, const u16* __restrict__ K,
    const u16* __restrict__ VT, u16* __restrict__ Oa) {
  __shared__ __align__(16) union SMem {
    u16 Vts[2][64 * LDW];     // V^T pair-tile [d][key0..127], dbuf (34.0 KB)
    float Of[4 * 64 * 16];    // epilogue combine slice (reuses V region)
  } sm;
  __shared__ float Lf[4 * 64 + 64];                    // l partials + inv

  const int b = blockIdx.x;
  const int h = b & 15;             // head -> XCD = h%8, 2 heads/XCD
  const int qt = 63 - (b >> 4);     // heavy q-tiles dispatch first (LPT)
  const int tid = threadIdx.x;
  const int wave = tid >> 6, lane = tid & 63;
  const int quad = lane >> 4, l15 = lane & 15;

  const size_t hoff = (size_t)h * L_SEQ * HEAD_DIM;
  const u16* __restrict__ Qh = Q + hoff;
  const u16* __restrict__ Kh = K + hoff;
  const u16* __restrict__ VTh = VT + hoff;

  const int q0 = qt * 64;
  const int np = (qt + 2) >> 1;     // pairs of 64-key tiles

  // K per-lane row pointer (A-frag rows = this wave's 16 keys of a tile)
  const u16* const Kg = Kh + (size_t)(wave * 16 + l15) * HEAD_DIM;

  // V staging: lane covers d = lane>>1 (and +32), 8 keys at (lane&1)*8
  // within the wave's 16-key stripe. Even tile cols [wave*16,+16),
  // odd tile at +64.
  const int vd0 = lane >> 1;
  const int vk  = (lane & 1) * 8;
  const int we0 = vd0 * LDW + wave * 16 + vk;
  const int we1 = (vd0 + 32) * LDW + wave * 16 + vk;
  const int wo0 = we0 + 64;
  const int wo1 = we1 + 64;
  const u16* const Vg0 = VTh + (size_t)vd0 * L_SEQ + wave * 16 + vk;
  const u16* const Vg1 = Vg0 + (size_t)32 * L_SEQ;

  // Q fragments (held in registers for the whole block)
  bf16x8 qf[4][2];
#pragma unroll
  for (int jq = 0; jq < 4; ++jq) {
    const u16* qrow = Qh + (size_t)(q0 + jq * 16 + l15) * HEAD_DIM;
    qf[jq][0] = *(const bf16x8*)(qrow + quad * 8);
    qf[jq][1] = *(const bf16x8*)(qrow + 32 + quad * 8);
  }

  floatx4 oacc[4][4] = {};
  float psum[4] = {};

  // --- prologue: pair0 -> LDS buf0; pair1 -> staging regs; K pair0 -> regs
  float4 se0 = *(const float4*)(Vg0);
  float4 se1 = *(const float4*)(Vg1);
  float4 so0 = *(const float4*)(Vg0 + 64);
  float4 so1 = *(const float4*)(Vg1 + 64);
  *(float4*)(&sm.Vts[0][we0]) = se0;
  *(float4*)(&sm.Vts[0][we1]) = se1;
  *(float4*)(&sm.Vts[0][wo0]) = so0;
  *(float4*)(&sm.Vts[0][wo1]) = so1;
  if (np > 1) {
    se0 = *(const float4*)(Vg0 + 128);
    se1 = *(const float4*)(Vg1 + 128);
    so0 = *(const float4*)(Vg0 + 192);
    so1 = *(const float4*)(Vg1 + 192);
  }
  bf16x8 kc00 = *(const bf16x8*)(Kg + quad * 8);
  bf16x8 kc01 = *(const bf16x8*)(Kg + 32 + quad * 8);
  bf16x8 kc10 = *(const bf16x8*)(Kg + (size_t)64 * HEAD_DIM + quad * 8);
  bf16x8 kc11 = *(const bf16x8*)(Kg + (size_t)64 * HEAD_DIM + 32 + quad * 8);

  for (int pt = 0; pt < np; ++pt) {
    // V frags for this pair: elems 0-3 = even-tile keys, 4-7 = odd-tile keys
    const u16* Vc = sm.Vts[pt & 1];
    bf16x8 vf[4];
#pragma unroll
    for (int nt = 0; nt < 4; ++nt) {
      const int rowb = (nt * 16 + l15) * LDW + wave * 16 + quad * 4;
      uint2 lo = *(const uint2*)(&Vc[rowb]);
      uint2 hi = *(const uint2*)(&Vc[rowb + 64]);
      u32x4 t;
      t.x = lo.x; t.y = lo.y; t.z = hi.x; t.w = hi.y;
      vf[nt] = __builtin_bit_cast(bf16x8, t);
    }

    // stage pair pt+1 into the other buffer; prefetch pair pt+2 into regs
    if (pt + 1 < np) {
      u16* Vn = sm.Vts[(pt + 1) & 1];
      *(float4*)(&Vn[we0]) = se0;
      *(float4*)(&Vn[we1]) = se1;
      *(float4*)(&Vn[wo0]) = so0;
      *(float4*)(&Vn[wo1]) = so1;
      if (pt + 2 < np) {
        const u16* src0 = Vg0 + (size_t)(pt + 2) * 128;
        const u16* src1 = Vg1 + (size_t)(pt + 2) * 128;
        se0 = *(const float4*)(src0);
        se1 = *(const float4*)(src1);
        so0 = *(const float4*)(src0 + 64);
        so1 = *(const float4*)(src1 + 64);
      }
    }

    // S^T for both tiles: s0/s1[jq][r] = S[key][q=jq*16+l15]
    floatx4 s0[4], s1[4];
#pragma unroll
    for (int jq = 0; jq < 4; ++jq) {
      floatx4 z = {};
      z = mfma32(kc00, qf[jq][0], z);
      z = mfma32(kc01, qf[jq][1], z);
      s0[jq] = z;
      floatx4 y = {};
      y = mfma32(kc10, qf[jq][0], y);
      y = mfma32(kc11, qf[jq][1], y);
      s1[jq] = y;
    }

    // reload K regs for pair pt+1 (after last use)
    if (pt + 1 < np) {
      const u16* Kn = Kg + (size_t)(pt + 1) * 128 * HEAD_DIM;
      kc00 = *(const bf16x8*)(Kn + quad * 8);
      kc01 = *(const bf16x8*)(Kn + 32 + quad * 8);
      kc10 = *(const bf16x8*)(Kn + (size_t)64 * HEAD_DIM + quad * 8);
      kc11 = *(const bf16x8*)(Kn + (size_t)64 * HEAD_DIM + 32 + quad * 8);
    }

    if (pt == np - 1) {            // causal mask (diagonal + overflow tiles)
      const int kbe = pt * 128 + wave * 16 + quad * 4;
#pragma unroll
      for (int jq = 0; jq < 4; ++jq) {
        const int qg = q0 + jq * 16 + l15;
#pragma unroll
        for (int r = 0; r < 4; ++r) {
          if (kbe + r > qg)      s0[jq][r] = -1e30f;
          if (kbe + 64 + r > qg) s1[jq][r] = -1e30f;
        }
      }
    }

    // P = exp2(s); pack pair-concatenated bf16 A-frag; accumulate l; PV
#pragma unroll
    for (int jq = 0; jq < 4; ++jq) {
      float p0 = hw_exp2(s0[jq][0]), p1 = hw_exp2(s0[jq][1]);
      float p2 = hw_exp2(s0[jq][2]), p3 = hw_exp2(s0[jq][3]);
      float r0 = hw_exp2(s1[jq][0]), r1 = hw_exp2(s1[jq][1]);
      float r2 = hw_exp2(s1[jq][2]), r3 = hw_exp2(s1[jq][3]);
      psum[jq] += ((p0 + p1) + (p2 + p3)) + ((r0 + r1) + (r2 + r3));
      u32x4 pw;
      pw.x = pack_bf16_trunc(p1, p0);
      pw.y = pack_bf16_trunc(p3, p2);
      pw.z = pack_bf16_trunc(r1, r0);
      pw.w = pack_bf16_trunc(r3, r2);
      bf16x8 pav = __builtin_bit_cast(bf16x8, pw);
#pragma unroll
      for (int nt = 0; nt < 4; ++nt)
        oacc[jq][nt] = mfma32(pav, vf[nt], oacc[jq][nt]);
    }
  }

  // ---- combine: sum 4 wave-partials of l and O, normalize, store ----
#pragma unroll
  for (int jq = 0; jq < 4; ++jq) {
    psum[jq] += __shfl_xor(psum[jq], 16, 64);
    psum[jq] += __shfl_xor(psum[jq], 32, 64);
  }
  if (quad == 0) {
#pragma unroll
    for (int jq = 0; jq < 4; ++jq)
      Lf[wave * 64 + jq * 16 + l15] = psum[jq];
  }
  __syncthreads();                 // all V reads retired -> Of may reuse LDS
  if (tid < 64) {
    float lt = Lf[tid] + Lf[64 + tid] + Lf[128 + tid] + Lf[192 + tid];
    Lf[256 + tid] = 1.0f / lt;
  }

  const int qc = tid >> 2, d4 = (tid & 3) * 4;
#pragma unroll
  for (int nt = 0; nt < 4; ++nt) {
#pragma unroll
    for (int jq = 0; jq < 4; ++jq)
#pragma unroll
      for (int r = 0; r < 4; ++r)
        sm.Of[wave * 1024 + (jq * 16 + quad * 4 + r) * 16 + l15] = oacc[jq][nt][r];
    __syncthreads();
    const float invq = Lf[256 + qc];
    floatx4 a0 = *(const floatx4*)&sm.Of[0 * 1024 + qc * 16 + d4];
    floatx4 a1 = *(const floatx4*)&sm.Of[1 * 1024 + qc * 16 + d4];
    floatx4 a2 = *(const floatx4*)&sm.Of[2 * 1024 + qc * 16 + d4];
    floatx4 a3 = *(const floatx4*)&sm.Of[3 * 1024 + qc * 16 + d4];
    floatx4 sum = (a0 + a1) + (a2 + a3);
    ushort4 o;
    o.x = f2bf(sum[0] * invq); o.y = f2bf(sum[1] * invq);
    o.z = f2bf(sum[2] * invq); o.w = f2bf(sum[3] * invq);
    *(ushort4*)(Oa + (size_t)(q0 + qc) * D_MODEL + (size_t)h * HEAD_DIM +
                nt * 16 + d4) = o;
    __syncthreads();
  }
}

// ---------------------------------------------------------------------------
extern "C" void kernel_launch(void* const* d_in, const int* in_sizes, int n_in,
                              void* d_out, int out_size, void* d_ws, size_t ws_size,
                              hipStream_t stream) {
  const float* x  = (const float*)d_in[0];
  const float* Wq = (const float*)d_in[1];
  const float* Wk = (const float*)d_in[2];
  const float* Wv = (const float*)d_in[3];
  const float* Wo = (const float*)d_in[4];
  float* out = (float*)d_out;

  const size_t XN = (size_t)L_SEQ * D_MODEL;
  const size_t WN = (size_t)D_MODEL * D_MODEL;
  const size_t HLHD = (size_t)N_HEADS * L_SEQ * HEAD_DIM;

  u16* x_bf  = (u16*)d_ws;
  u16* wq_bf = x_bf + XN;
  u16* wk_bf = wq_bf + WN;
  u16* wv_bf = wk_bf + WN;
  u16* wo_bf = wv_bf + WN;
  u16* q_ws  = wo_bf + WN;
  u16* k_ws  = q_ws + HLHD;
  u16* vT_ws = k_ws + HLHD;
  u16* a_ws  = vT_ws + HLHD;

  dim3 gc(1024, 1, 5);
  cvt_kernel<<<gc, 256, 0, stream>>>(x, Wq, Wk, Wv, Wo,
                                     x_bf, wq_bf, wk_bf, wv_bf, wo_bf);

  dim3 gqkv(768, 1, 1);
  qkv_gemm_kernel<<<gqkv, 512, 0, stream>>>(x_bf, wq_bf, wk_bf, wv_bf,
                                            q_ws, k_ws, vT_ws);

  dim3 ga(1024, 1, 1);
  attn_kernel<<<ga, 256, 0, stream>>>(q_ws, k_ws, vT_ws, a_ws);

  dim3 go(512, 1, 1);
  out_gemm_kernel<<<go, 512, 0, stream>>>(a_ws, wo_bf, out);
}

// Round 13
// 188.531 us; speedup vs baseline: 1.0554x; 1.0554x over previous
//
#include <hip/hip_runtime.h>
#include <hip/hip_bf16.h>
#include <stdint.h>

#define L_SEQ   4096
#define D_MODEL 1024
#define N_HEADS 16
#define HEAD_DIM 64

typedef uint16_t u16;
typedef __bf16 bf16x8 __attribute__((ext_vector_type(8)));
typedef uint32_t u32x4 __attribute__((ext_vector_type(4)));
typedef float floatx4 __attribute__((ext_vector_type(4)));

__device__ __forceinline__ floatx4 mfma32(bf16x8 a, bf16x8 b, floatx4 c) {
  return __builtin_amdgcn_mfma_f32_16x16x32_bf16(a, b, c, 0, 0, 0);
}

__device__ __forceinline__ float hw_exp2(float x) {
  return __builtin_amdgcn_exp2f(x);
}

__device__ __forceinline__ uint32_t fbits(float f) {
  union { float f; uint32_t u; } x; x.f = f; return x.u;
}

// pack two f32 -> two truncated bf16 in one v_perm_b32
__device__ __forceinline__ uint32_t pack_bf16_trunc(float f1, float f0) {
  return __builtin_amdgcn_perm(fbits(f1), fbits(f0), 0x07060302u);
}

// async global->LDS 16B per lane; LDS dest = wave-uniform base + lane*16
__device__ __forceinline__ void load16_lds(const u16* g, u16* l) {
  __builtin_amdgcn_global_load_lds(
      (const __attribute__((address_space(1))) void*)g,
      (__attribute__((address_space(3))) void*)l, 16, 0, 0);
}

// round-to-nearest-even f32 -> bf16 bits
__device__ __forceinline__ u16 f2bf(float f) {
  uint32_t u = fbits(f);
  uint32_t r = u + 0x7FFFu + ((u >> 16) & 1u);
  return (u16)(r >> 16);
}

// 0.125 * log2(e): folds softmax scale + exp->exp2 conversion into Q.
#define Q_PRESCALE 0.18033688011112042f

// ---------------------------------------------------------------------------
// f32 -> bf16 conversion pre-pass. grid.z selects tensor (0=x, 1..4=W).
// 8 elems/thread (2x float4 read, 2x ushort4 write). (R20-proven)
// ---------------------------------------------------------------------------
__global__ __launch_bounds__(256) void cvt_kernel(
    const float* __restrict__ x,  const float* __restrict__ wq,
    const float* __restrict__ wk, const float* __restrict__ wv,
    const float* __restrict__ wo,
    u16* __restrict__ xb, u16* __restrict__ wqb, u16* __restrict__ wkb,
    u16* __restrict__ wvb, u16* __restrict__ wob) {
  const int z = blockIdx.z;
  const float* s; u16* d; int n;
  if (z == 0)      { s = x;  d = xb;  n = L_SEQ * D_MODEL; }
  else if (z == 1) { s = wq; d = wqb; n = D_MODEL * D_MODEL; }
  else if (z == 2) { s = wk; d = wkb; n = D_MODEL * D_MODEL; }
  else if (z == 3) { s = wv; d = wvb; n = D_MODEL * D_MODEL; }
  else             { s = wo; d = wob; n = D_MODEL * D_MODEL; }
  const int stride = gridDim.x * 256 * 8;
  for (int i = (blockIdx.x * 256 + threadIdx.x) * 8; i < n; i += stride) {
    float4 v0 = *(const float4*)(s + i);
    float4 v1 = *(const float4*)(s + i + 4);
    ushort4 o0, o1;
    o0.x = f2bf(v0.x); o0.y = f2bf(v0.y); o0.z = f2bf(v0.z); o0.w = f2bf(v0.w);
    o1.x = f2bf(v1.x); o1.y = f2bf(v1.y); o1.z = f2bf(v1.z); o1.w = f2bf(v1.w);
    *(ushort4*)(d + i) = o0;
    *(ushort4*)(d + i + 4) = o1;
  }
}

// ---------------------------------------------------------------------------
// Merged Q/K/V^T GEMM. R23: T4 counted-vmcnt on the UNCHANGED 2-buffer
// layout (R22's 3-buffer ring cut occupancy 4->3 blocks/CU -- confounded
// test; reverted). Order per iter:
//   lgkmcnt(0)          my LDS reads of buf[(kk+1)&1] (iter kk-1) retired
//   s_barrier           every wave's reads retired -> safe to overwrite
//   stage(kk+1)         2 loads into buf[(kk+1)&1]
//   vmcnt(2)            retire stage(kk) (oldest 2 of 4 outstanding);
//                       the just-issued prefetch STAYS IN FLIGHT
// vs __syncthreads' implicit vmcnt(0) which drained it every iter (the
// documented ~20% m97-structure stall). LDS 32 KB -> 4 blocks/CU kept.
// ---------------------------------------------------------------------------
__global__ __launch_bounds__(512) void qkv_gemm_kernel(
    const u16* __restrict__ X,
    const u16* __restrict__ Wq, const u16* __restrict__ Wk, const u16* __restrict__ Wv,
    u16* __restrict__ Qo, u16* __restrict__ Ko, u16* __restrict__ VTo) {
  constexpr int BK = 32, Kdim = D_MODEL, NIT = Kdim / BK;
  __shared__ __align__(16) u16 As[2][128 * BK];
  __shared__ __align__(16) u16 Bs[2][128 * BK];

  const int b = blockIdx.x;
  const int g = b & 7, i2 = b >> 3;
  const int z = i2 % 3, j = i2 / 3;          // z fastest within XCD stream
  const int x = (g & 3) * 8 + (j & 7);       // 32 m-tiles (seq for z<2)
  const int y = (g >> 2) * 4 + (j >> 3);     // 8 n-tiles (dout for z<2)

  const u16* __restrict__ A;
  const u16* __restrict__ B;
  int m0, n0;
  if (z < 2) { A = X; B = z ? Wk : Wq; m0 = x * 128; n0 = y * 128; }
  else       { A = Wv; B = X;          m0 = y * 128; n0 = x * 128; }

  const int tid = threadIdx.x;               // 0..511
  const int wave = tid >> 6, lane = tid & 63;
  const int wm = wave & 1, wn = wave >> 1;   // 2 x 4 wave grid
  const int quad = lane >> 4, l15 = lane & 15;

  floatx4 acc[4][2] = {};

  // staging: thread t covers row t>>2, 8-col chunk (t&3)*8 of the 128x32 tile
  const int r0 = tid >> 2, cc0 = (tid & 3) * 8;

  auto stage = [&](int k0, int sel) {
    load16_lds(&A[(size_t)(m0 + r0) * Kdim + k0 + cc0], &As[sel][wave * 512]);
    load16_lds(&B[(size_t)(n0 + r0) * Kdim + k0 + cc0], &Bs[sel][wave * 512]);
  };

  stage(0, 0);
  for (int kk = 0; kk < NIT; ++kk) {
    asm volatile("s_waitcnt lgkmcnt(0)" ::: "memory");  // my prev reads done
    __builtin_amdgcn_s_barrier();                       // all waves' done
    if (kk + 1 < NIT) {
      stage((kk + 1) * BK, (kk + 1) & 1);               // 2 new loads
      asm volatile("s_waitcnt vmcnt(2)" ::: "memory");  // retire stage(kk)
    } else {
      asm volatile("s_waitcnt vmcnt(0)" ::: "memory");  // final drain
    }

    const u16* Asc = As[kk & 1];
    const u16* Bsc = Bs[kk & 1];

    bf16x8 af[4], wf[2];
#pragma unroll
    for (int i = 0; i < 4; ++i)
      af[i] = *(const bf16x8*)(&Asc[(wm * 64 + i * 16 + l15) * BK + quad * 8]);
#pragma unroll
    for (int jn = 0; jn < 2; ++jn)
      wf[jn] = *(const bf16x8*)(&Bsc[(wn * 32 + jn * 16 + l15) * BK + quad * 8]);
#pragma unroll
    for (int i = 0; i < 4; ++i)
#pragma unroll
      for (int jn = 0; jn < 2; ++jn)
        acc[i][jn] = mfma32(af[i], wf[jn], acc[i][jn]);
  }

  const float scale = (z == 0) ? Q_PRESCALE : 1.0f;
  u16* __restrict__ C = (z == 0) ? Qo : (z == 1) ? Ko : VTo;
#pragma unroll
  for (int i = 0; i < 4; ++i) {
    const int mb = m0 + wm * 64 + i * 16 + quad * 4;
#pragma unroll
    for (int jn = 0; jn < 2; ++jn) {
      const int n = n0 + wn * 32 + jn * 16 + l15;
#pragma unroll
      for (int r = 0; r < 4; ++r) {
        const int m = mb + r;
        if (z < 2) {
          C[(size_t)(n >> 6) * (size_t)L_SEQ * HEAD_DIM + (size_t)m * HEAD_DIM + (n & 63)] =
              f2bf(acc[i][jn][r] * scale);
        } else {
          C[(size_t)(m >> 6) * (size_t)L_SEQ * HEAD_DIM + (size_t)(m & 63) * L_SEQ + n] =
              f2bf(acc[i][jn][r]);
        }
      }
    }
  }
}

// ---------------------------------------------------------------------------
// Output GEMM: out = att @ Wo^T, f32 out. R23: reverted to R20-exact form
// (512-thread, 2D grid, __syncthreads double-buffer). R21's swizzle was
// neutral; R22's counted-vmcnt regressed -- both removed.
// ---------------------------------------------------------------------------
__global__ __launch_bounds__(512) void out_gemm_kernel(
    const u16* __restrict__ A, const u16* __restrict__ W, float* __restrict__ C) {
  constexpr int BK = 32, Kdim = D_MODEL, NIT = Kdim / BK;
  __shared__ __align__(16) u16 As[2][128 * BK];
  __shared__ __align__(16) u16 Bs[2][64 * BK];

  const int tid = threadIdx.x;               // 0..511
  const int wave = tid >> 6, lane = tid & 63;
  const int wm = wave & 1, wn = wave >> 1;   // 2m x 4n wave grid
  const int quad = lane >> 4, l15 = lane & 15;
  const int m0 = blockIdx.x * 128, n0 = blockIdx.y * 64;

  floatx4 acc[4] = {};

  // staging: thread t covers row t>>2, 8-col chunk (t&3)*8
  const int r0 = tid >> 2, cc0 = (tid & 3) * 8;

  auto stage = [&](int k0, int sel) {
    load16_lds(&A[(size_t)(m0 + r0) * Kdim + k0 + cc0], &As[sel][wave * 512]);
    if (wave < 4)                            // 64-row B tile: waves 0-3
      load16_lds(&W[(size_t)(n0 + r0) * Kdim + k0 + cc0], &Bs[sel][wave * 512]);
  };

  stage(0, 0);
  for (int kk = 0; kk < NIT; ++kk) {
    __syncthreads();
    if (kk + 1 < NIT) stage((kk + 1) * BK, (kk + 1) & 1);
    const u16* Asc = As[kk & 1];
    const u16* Bsc = Bs[kk & 1];

    bf16x8 af[4], wf;
#pragma unroll
    for (int i = 0; i < 4; ++i)
      af[i] = *(const bf16x8*)(&Asc[(wm * 64 + i * 16 + l15) * BK + quad * 8]);
    wf = *(const bf16x8*)(&Bsc[(wn * 16 + l15) * BK + quad * 8]);
#pragma unroll
    for (int i = 0; i < 4; ++i)
      acc[i] = mfma32(af[i], wf, acc[i]);
  }

#pragma unroll
  for (int i = 0; i < 4; ++i) {
    const int mb = m0 + wm * 64 + i * 16 + quad * 4;
    const int n = n0 + wn * 16 + l15;
#pragma unroll
    for (int r = 0; r < 4; ++r)
      C[(size_t)(mb + r) * D_MODEL + n] = acc[i][r];
  }
}

// ---------------------------------------------------------------------------
// Causal flash attention (R14 inner loop, single 1024-block dispatch --
// proven 64.5us; all in-structure levers measured null R13-R16). Unchanged.
// ---------------------------------------------------------------------------
#define LDW 136
__global__ __launch_bounds__(256, 2) void attn_kernel(
    const u16* __restrict__ Q, const u16* __restrict__ K,
    const u16* __restrict__ VT, u16* __restrict__ Oa) {
  __shared__ __align__(16) union SMem {
    u16 Vts[2][64 * LDW];     // V^T pair-tile [d][key0..127], dbuf (34.0 KB)
    float Of[4 * 64 * 16];    // epilogue combine slice (reuses V region)
  } sm;
  __shared__ float Lf[4 * 64 + 64];                    // l partials + inv

  const int b = blockIdx.x;
  const int h = b & 15;             // head -> XCD = h%8, 2 heads/XCD
  const int qt = 63 - (b >> 4);     // heavy q-tiles dispatch first (LPT)
  const int tid = threadIdx.x;
  const int wave = tid >> 6, lane = tid & 63;
  const int quad = lane >> 4, l15 = lane & 15;

  const size_t hoff = (size_t)h * L_SEQ * HEAD_DIM;
  const u16* __restrict__ Qh = Q + hoff;
  const u16* __restrict__ Kh = K + hoff;
  const u16* __restrict__ VTh = VT + hoff;

  const int q0 = qt * 64;
  const int np = (qt + 2) >> 1;     // pairs of 64-key tiles

  // K per-lane row pointer (A-frag rows = this wave's 16 keys of a tile)
  const u16* const Kg = Kh + (size_t)(wave * 16 + l15) * HEAD_DIM;

  // V staging: lane covers d = lane>>1 (and +32), 8 keys at (lane&1)*8
  // within the wave's 16-key stripe. Even tile cols [wave*16,+16),
  // odd tile at +64.
  const int vd0 = lane >> 1;
  const int vk  = (lane & 1) * 8;
  const int we0 = vd0 * LDW + wave * 16 + vk;
  const int we1 = (vd0 + 32) * LDW + wave * 16 + vk;
  const int wo0 = we0 + 64;
  const int wo1 = we1 + 64;
  const u16* const Vg0 = VTh + (size_t)vd0 * L_SEQ + wave * 16 + vk;
  const u16* const Vg1 = Vg0 + (size_t)32 * L_SEQ;

  // Q fragments (held in registers for the whole block)
  bf16x8 qf[4][2];
#pragma unroll
  for (int jq = 0; jq < 4; ++jq) {
    const u16* qrow = Qh + (size_t)(q0 + jq * 16 + l15) * HEAD_DIM;
    qf[jq][0] = *(const bf16x8*)(qrow + quad * 8);
    qf[jq][1] = *(const bf16x8*)(qrow + 32 + quad * 8);
  }

  floatx4 oacc[4][4] = {};
  float psum[4] = {};

  // --- prologue: pair0 -> LDS buf0; pair1 -> staging regs; K pair0 -> regs
  float4 se0 = *(const float4*)(Vg0);
  float4 se1 = *(const float4*)(Vg1);
  float4 so0 = *(const float4*)(Vg0 + 64);
  float4 so1 = *(const float4*)(Vg1 + 64);
  *(float4*)(&sm.Vts[0][we0]) = se0;
  *(float4*)(&sm.Vts[0][we1]) = se1;
  *(float4*)(&sm.Vts[0][wo0]) = so0;
  *(float4*)(&sm.Vts[0][wo1]) = so1;
  if (np > 1) {
    se0 = *(const float4*)(Vg0 + 128);
    se1 = *(const float4*)(Vg1 + 128);
    so0 = *(const float4*)(Vg0 + 192);
    so1 = *(const float4*)(Vg1 + 192);
  }
  bf16x8 kc00 = *(const bf16x8*)(Kg + quad * 8);
  bf16x8 kc01 = *(const bf16x8*)(Kg + 32 + quad * 8);
  bf16x8 kc10 = *(const bf16x8*)(Kg + (size_t)64 * HEAD_DIM + quad * 8);
  bf16x8 kc11 = *(const bf16x8*)(Kg + (size_t)64 * HEAD_DIM + 32 + quad * 8);

  for (int pt = 0; pt < np; ++pt) {
    // V frags for this pair: elems 0-3 = even-tile keys, 4-7 = odd-tile keys
    const u16* Vc = sm.Vts[pt & 1];
    bf16x8 vf[4];
#pragma unroll
    for (int nt = 0; nt < 4; ++nt) {
      const int rowb = (nt * 16 + l15) * LDW + wave * 16 + quad * 4;
      uint2 lo = *(const uint2*)(&Vc[rowb]);
      uint2 hi = *(const uint2*)(&Vc[rowb + 64]);
      u32x4 t;
      t.x = lo.x; t.y = lo.y; t.z = hi.x; t.w = hi.y;
      vf[nt] = __builtin_bit_cast(bf16x8, t);
    }

    // stage pair pt+1 into the other buffer; prefetch pair pt+2 into regs
    if (pt + 1 < np) {
      u16* Vn = sm.Vts[(pt + 1) & 1];
      *(float4*)(&Vn[we0]) = se0;
      *(float4*)(&Vn[we1]) = se1;
      *(float4*)(&Vn[wo0]) = so0;
      *(float4*)(&Vn[wo1]) = so1;
      if (pt + 2 < np) {
        const u16* src0 = Vg0 + (size_t)(pt + 2) * 128;
        const u16* src1 = Vg1 + (size_t)(pt + 2) * 128;
        se0 = *(const float4*)(src0);
        se1 = *(const float4*)(src1);
        so0 = *(const float4*)(src0 + 64);
        so1 = *(const float4*)(src1 + 64);
      }
    }

    // S^T for both tiles: s0/s1[jq][r] = S[key][q=jq*16+l15]
    floatx4 s0[4], s1[4];
#pragma unroll
    for (int jq = 0; jq < 4; ++jq) {
      floatx4 z = {};
      z = mfma32(kc00, qf[jq][0], z);
      z = mfma32(kc01, qf[jq][1], z);
      s0[jq] = z;
      floatx4 y = {};
      y = mfma32(kc10, qf[jq][0], y);
      y = mfma32(kc11, qf[jq][1], y);
      s1[jq] = y;
    }

    // reload K regs for pair pt+1 (after last use)
    if (pt + 1 < np) {
      const u16* Kn = Kg + (size_t)(pt + 1) * 128 * HEAD_DIM;
      kc00 = *(const bf16x8*)(Kn + quad * 8);
      kc01 = *(const bf16x8*)(Kn + 32 + quad * 8);
      kc10 = *(const bf16x8*)(Kn + (size_t)64 * HEAD_DIM + quad * 8);
      kc11 = *(const bf16x8*)(Kn + (size_t)64 * HEAD_DIM + 32 + quad * 8);
    }

    if (pt == np - 1) {            // causal mask (diagonal + overflow tiles)
      const int kbe = pt * 128 + wave * 16 + quad * 4;
#pragma unroll
      for (int jq = 0; jq < 4; ++jq) {
        const int qg = q0 + jq * 16 + l15;
#pragma unroll
        for (int r = 0; r < 4; ++r) {
          if (kbe + r > qg)      s0[jq][r] = -1e30f;
          if (kbe + 64 + r > qg) s1[jq][r] = -1e30f;
        }
      }
    }

    // P = exp2(s); pack pair-concatenated bf16 A-frag; accumulate l; PV
#pragma unroll
    for (int jq = 0; jq < 4; ++jq) {
      float p0 = hw_exp2(s0[jq][0]), p1 = hw_exp2(s0[jq][1]);
      float p2 = hw_exp2(s0[jq][2]), p3 = hw_exp2(s0[jq][3]);
      float r0 = hw_exp2(s1[jq][0]), r1 = hw_exp2(s1[jq][1]);
      float r2 = hw_exp2(s1[jq][2]), r3 = hw_exp2(s1[jq][3]);
      psum[jq] += ((p0 + p1) + (p2 + p3)) + ((r0 + r1) + (r2 + r3));
      u32x4 pw;
      pw.x = pack_bf16_trunc(p1, p0);
      pw.y = pack_bf16_trunc(p3, p2);
      pw.z = pack_bf16_trunc(r1, r0);
      pw.w = pack_bf16_trunc(r3, r2);
      bf16x8 pav = __builtin_bit_cast(bf16x8, pw);
#pragma unroll
      for (int nt = 0; nt < 4; ++nt)
        oacc[jq][nt] = mfma32(pav, vf[nt], oacc[jq][nt]);
    }
  }

  // ---- combine: sum 4 wave-partials of l and O, normalize, store ----
#pragma unroll
  for (int jq = 0; jq < 4; ++jq) {
    psum[jq] += __shfl_xor(psum[jq], 16, 64);
    psum[jq] += __shfl_xor(psum[jq], 32, 64);
  }
  if (quad == 0) {
#pragma unroll
    for (int jq = 0; jq < 4; ++jq)
      Lf[wave * 64 + jq * 16 + l15] = psum[jq];
  }
  __syncthreads();                 // all V reads retired -> Of may reuse LDS
  if (tid < 64) {
    float lt = Lf[tid] + Lf[64 + tid] + Lf[128 + tid] + Lf[192 + tid];
    Lf[256 + tid] = 1.0f / lt;
  }

  const int qc = tid >> 2, d4 = (tid & 3) * 4;
#pragma unroll
  for (int nt = 0; nt < 4; ++nt) {
#pragma unroll
    for (int jq = 0; jq < 4; ++jq)
#pragma unroll
      for (int r = 0; r < 4; ++r)
        sm.Of[wave * 1024 + (jq * 16 + quad * 4 + r) * 16 + l15] = oacc[jq][nt][r];
    __syncthreads();
    const float invq = Lf[256 + qc];
    floatx4 a0 = *(const floatx4*)&sm.Of[0 * 1024 + qc * 16 + d4];
    floatx4 a1 = *(const floatx4*)&sm.Of[1 * 1024 + qc * 16 + d4];
    floatx4 a2 = *(const floatx4*)&sm.Of[2 * 1024 + qc * 16 + d4];
    floatx4 a3 = *(const floatx4*)&sm.Of[3 * 1024 + qc * 16 + d4];
    floatx4 sum = (a0 + a1) + (a2 + a3);
    ushort4 o;
    o.x = f2bf(sum[0] * invq); o.y = f2bf(sum[1] * invq);
    o.z = f2bf(sum[2] * invq); o.w = f2bf(sum[3] * invq);
    *(ushort4*)(Oa + (size_t)(q0 + qc) * D_MODEL + (size_t)h * HEAD_DIM +
                nt * 16 + d4) = o;
    __syncthreads();
  }
}

// ---------------------------------------------------------------------------
extern "C" void kernel_launch(void* const* d_in, const int* in_sizes, int n_in,
                              void* d_out, int out_size, void* d_ws, size_t ws_size,
                              hipStream_t stream) {
  const float* x  = (const float*)d_in[0];
  const float* Wq = (const float*)d_in[1];
  const float* Wk = (const float*)d_in[2];
  const float* Wv = (const float*)d_in[3];
  const float* Wo = (const float*)d_in[4];
  float* out = (float*)d_out;

  const size_t XN = (size_t)L_SEQ * D_MODEL;
  const size_t WN = (size_t)D_MODEL * D_MODEL;
  const size_t HLHD = (size_t)N_HEADS * L_SEQ * HEAD_DIM;

  u16* x_bf  = (u16*)d_ws;
  u16* wq_bf = x_bf + XN;
  u16* wk_bf = wq_bf + WN;
  u16* wv_bf = wk_bf + WN;
  u16* wo_bf = wv_bf + WN;
  u16* q_ws  = wo_bf + WN;
  u16* k_ws  = q_ws + HLHD;
  u16* vT_ws = k_ws + HLHD;
  u16* a_ws  = vT_ws + HLHD;

  dim3 gc(1024, 1, 5);
  cvt_kernel<<<gc, 256, 0, stream>>>(x, Wq, Wk, Wv, Wo,
                                     x_bf, wq_bf, wk_bf, wv_bf, wo_bf);

  dim3 gqkv(768, 1, 1);
  qkv_gemm_kernel<<<gqkv, 512, 0, stream>>>(x_bf, wq_bf, wk_bf, wv_bf,
                                            q_ws, k_ws, vT_ws);

  dim3 ga(1024, 1, 1);
  attn_kernel<<<ga, 256, 0, stream>>>(q_ws, k_ws, vT_ws, a_ws);

  dim3 go(L_SEQ / 128, D_MODEL / 64, 1);
  out_gemm_kernel<<<go, 512, 0, stream>>>(a_ws, wo_bf, out);
}